// Round 8
// baseline (159.416 us; speedup 1.0000x reference)
//
#include <hip/hip_runtime.h>
#include <hip/hip_bf16.h>

#define S_LEN 2048
#define EMB 1024
#define NH 16
#define HD 64
// M = B*S = 4096 rows

typedef __attribute__((ext_vector_type(8))) __bf16 bf16x8;
typedef __attribute__((ext_vector_type(4))) float f32x4;
typedef __attribute__((ext_vector_type(16))) float f32x16;
typedef __attribute__((ext_vector_type(4))) unsigned int u32x4;

__device__ inline void gload_lds16(const void* g, void* l) {
    __builtin_amdgcn_global_load_lds(
        (const __attribute__((address_space(1))) unsigned int*)g,
        (__attribute__((address_space(3))) unsigned int*)l, 16, 0, 0);
}

// ---------------------------------------------------------------------------
// Kernel 0: fp32 -> bf16 conversion of x, qkv_w, out_w in ONE launch.
// ---------------------------------------------------------------------------
__global__ __launch_bounds__(256) void cvt_all(
    const float* __restrict__ x, const float* __restrict__ wq,
    const float* __restrict__ wo,
    __hip_bfloat16* __restrict__ xb, __hip_bfloat16* __restrict__ wqb,
    __hip_bfloat16* __restrict__ wob)
{
    const long C_X = (long)4096 * 1024 / 4;       // 1,048,576
    const long C_WQ = (long)3072 * 1024 / 4;      // 786,432
    long c = (long)blockIdx.x * 256 + threadIdx.x;
    const float* in;
    __hip_bfloat16* out;
    if (c < C_X) { in = x; out = xb; }
    else if (c < C_X + C_WQ) { in = wq; out = wqb; c -= C_X; }
    else { in = wo; out = wob; c -= C_X + C_WQ; }
    long i = c * 4;
    float4 v = *(const float4*)(in + i);
    __hip_bfloat16 b0 = __float2bfloat16(v.x);
    __hip_bfloat16 b1 = __float2bfloat16(v.y);
    __hip_bfloat16 b2 = __float2bfloat16(v.z);
    __hip_bfloat16 b3 = __float2bfloat16(v.w);
    ushort4 o = {*(unsigned short*)&b0, *(unsigned short*)&b1,
                 *(unsigned short*)&b2, *(unsigned short*)&b3};
    *(ushort4*)(out + i) = o;
}

// ---------------------------------------------------------------------------
// MFMA GEMM core (m97 structure): C = A @ B^T, 128x128 tile, BK=64, 4 waves.
// EPI=0: quantum epilogue (cos*cos, scatter Q/K/Vt).  EPI=1: fp32 C store.
// Q is pre-scaled by 0.125*log2(e) so attention can use exp2 directly.
// ---------------------------------------------------------------------------
template <int EPI>
__global__ __launch_bounds__(256) void gemm_mfma(
    const __hip_bfloat16* __restrict__ A,   // [M][1024]
    const __hip_bfloat16* __restrict__ B,   // [N][1024]
    const float* __restrict__ qp,           // [64] (EPI=0)
    __hip_bfloat16* __restrict__ Q,         // EPI=0 outputs
    __hip_bfloat16* __restrict__ Kp,
    __hip_bfloat16* __restrict__ Vt,
    float* __restrict__ C)                  // EPI=1 output
{
    const int Kd = 1024;
    __shared__ __align__(16) char Ash[128 * 128];
    __shared__ __align__(16) char Bsh[128 * 128];

    const int t  = threadIdx.x;
    const int w  = t >> 6;
    const int l  = t & 63;
    const int lg = l >> 4, lm = l & 15;
    const int wr = w >> 1, wc = w & 1;
    const int m0 = blockIdx.y * 128;
    const int n0 = blockIdx.x * 128;

    const int r8 = l >> 3;
    const int sb = ((l & 7) * 16) ^ (r8 << 4);
    const char* srcA = (const char*)A + ((long)(m0 + w * 32 + r8) * Kd) * 2 + sb;
    const char* srcB = (const char*)B + ((long)(n0 + w * 32 + r8) * Kd) * 2 + sb;

    f32x4 acc[4][4];
#pragma unroll
    for (int i = 0; i < 4; i++)
#pragma unroll
        for (int j = 0; j < 4; j++) acc[i][j] = (f32x4){0.f, 0.f, 0.f, 0.f};

    for (int kt = 0; kt < Kd * 2; kt += 128) {
#pragma unroll
        for (int j = 0; j < 4; j++) {
            gload_lds16(srcA + (long)j * 8 * Kd * 2 + kt, Ash + (w * 32 + j * 8) * 128);
            gload_lds16(srcB + (long)j * 8 * Kd * 2 + kt, Bsh + (w * 32 + j * 8) * 128);
        }
        __syncthreads();
#pragma unroll
        for (int kk = 0; kk < 2; kk++) {
            bf16x8 af[4], bfr[4];
            const int sw = (lm & 7) << 4;
            const int co = (kk * 64 + lg * 16);
#pragma unroll
            for (int mi = 0; mi < 4; mi++)
                af[mi] = *(const bf16x8*)(Ash + (wr * 64 + mi * 16 + lm) * 128 + (co ^ sw));
#pragma unroll
            for (int ni = 0; ni < 4; ni++)
                bfr[ni] = *(const bf16x8*)(Bsh + (wc * 64 + ni * 16 + lm) * 128 + (co ^ sw));
#pragma unroll
            for (int mi = 0; mi < 4; mi++)
#pragma unroll
                for (int ni = 0; ni < 4; ni++)
                    acc[mi][ni] = __builtin_amdgcn_mfma_f32_16x16x32_bf16(
                        af[mi], bfr[ni], acc[mi][ni], 0, 0, 0);
        }
        __syncthreads();
    }

    if constexpr (EPI == 0) {
        const int which = n0 >> 10;
        float cqp[4];
#pragma unroll
        for (int ni = 0; ni < 4; ni++)
            cqp[ni] = __cosf(qp[(wc * 64 + ni * 16 + lm) & 63]);
#pragma unroll
        for (int mi = 0; mi < 4; mi++) {
#pragma unroll
            for (int r = 0; r < 4; r++) {
                int m = m0 + wr * 64 + mi * 16 + lg * 4 + r;
                int b = m >> 11, s = m & 2047;
#pragma unroll
                for (int ni = 0; ni < 4; ni++) {
                    int n = n0 + wc * 64 + ni * 16 + lm;
                    int d = n & 63;
                    int h = (n & 1023) >> 6;
                    int bh = b * NH + h;
                    float val = __cosf(acc[mi][ni][r]) * cqp[ni];
                    if (which == 0)  // 0.125 * log2(e) folded for exp2 softmax
                        Q[((long)bh * S_LEN + s) * HD + d] = __float2bfloat16(val * 0.180336880f);
                    else if (which == 1)
                        Kp[((long)bh * S_LEN + s) * HD + d] = __float2bfloat16(val);
                    else
                        Vt[((long)bh * HD + d) * S_LEN + s] = __float2bfloat16(val);
                }
            }
        }
    } else {
#pragma unroll
        for (int mi = 0; mi < 4; mi++)
#pragma unroll
            for (int r = 0; r < 4; r++) {
                int m = m0 + wr * 64 + mi * 16 + lg * 4 + r;
#pragma unroll
                for (int ni = 0; ni < 4; ni++) {
                    int n = n0 + wc * 64 + ni * 16 + lm;
                    C[(long)m * 1024 + n] = acc[mi][ni][r];
                }
            }
    }
}

// ---------------------------------------------------------------------------
// Kernel 2: MFMA flash attention, 32x32x16 shape, P fully IN-REGISTER (T12).
// Block = 2 waves x 32 q-rows (QBLK=64, grid 1024). K/V double-buffered in
// swizzled LDS via global_load_lds (round-7 scheme, one barrier/tile).
// Swapped QK^T: mfma(K,Q) -> S^T, col=q=lane&31 (m74/m101 C/D layout),
// key=(r&3)+8*(r>>2)+4*hi per reg. Fixed-max exp2 softmax (bound 8*log2e
// pre-folded; Q scaled by 0.125*log2e). P -> PV A-fragments via
// 8x v_cvt_pk_bf16_f32 + 4x v_permlane32_swap_b32 per 32-key block:
//   c0=pk(p0,p1) c1=pk(p2,p3) c2=pk(p4,p5) c3=pk(p6,p7) (+c4..c7)
//   swap(c0,c2), swap(c1,c3) -> PA[ks]={c0,c1,c2,c3}  (both lane halves)
// PV: mfma(PA[ks], Vt-frag) -> O[q over regs][d=lane&31]. No P LDS at all.
// ---------------------------------------------------------------------------
__global__ __launch_bounds__(128) void attn_mfma(
    const __hip_bfloat16* __restrict__ Q,
    const __hip_bfloat16* __restrict__ K,
    const __hip_bfloat16* __restrict__ Vt,  // [B,H,D,S]
    __hip_bfloat16* __restrict__ O)
{
    __shared__ __align__(16) char Ksh[2][64 * 128];  // 64 keys x 64 d (swz)
    __shared__ __align__(16) char Vsh[2][64 * 128];  // 64 d x 64 keys (swz)

    const int bh = blockIdx.y;
    const int b  = bh >> 4, h = bh & 15;
    const int q0 = blockIdx.x * 64;
    const int t  = threadIdx.x;          // 0..127
    const int w  = t >> 6;               // wave 0..1
    const int l  = t & 63;
    const int lo5 = l & 31;
    const int hi  = l >> 5;

    // Q fragments (pre-scaled by 0.125*log2e): lane holds Q[q=w*32+lo5][k-slices]
    const char* Qr = (const char*)(Q + ((long)bh * S_LEN + q0 + w * 32 + lo5) * HD);
    bf16x8 qf[4];
#pragma unroll
    for (int ks = 0; ks < 4; ks++)
        qf[ks] = *(const bf16x8*)(Qr + ks * 32 + hi * 16);

    f32x16 oacc[2] = {};
    float lsum = 0.f;
    const float EXPB = 11.54156033f;  // 8 * log2(e)

    const char* Kgb = (const char*)(K + (long)bh * S_LEN * HD);
    const char* Vgb = (const char*)(Vt + (long)bh * HD * S_LEN);

    // DMA staging: chunk c = t + 128*j -> LDS row c>>3, 16B col c&7.
    // Linear LDS dest; source byte pre-swizzled by ((row&7)<<4).
    const int sbst = ((t & 7) * 16) ^ (((t >> 3) & 7) << 4);
    const char* Ksrc = Kgb + (long)(t >> 3) * 128 + sbst;   // +kt*128 + j*2048
    const char* Vsrc = Vgb + (long)(t >> 3) * 4096 + sbst;  // +kt*2  + j*65536

#define STAGE(buf, ktv)                                                        \
    do {                                                                       \
        _Pragma("unroll") for (int j = 0; j < 4; j++) {                        \
            gload_lds16(Ksrc + (long)(ktv) * 128 + j * 2048,                   \
                        Ksh[buf] + w * 1024 + j * 2048);                       \
            gload_lds16(Vsrc + (long)(ktv) * 2 + j * 65536,                    \
                        Vsh[buf] + w * 1024 + j * 2048);                       \
        }                                                                      \
    } while (0)

    STAGE(0, 0);

    const int swr = (lo5 & 7) << 4;  // read swizzle (row&7 == lo5&7 for both n0)
    int cur = 0;
    for (int kt = 0; kt < S_LEN; kt += 64) {
        __syncthreads();  // buf[cur] staged; prev reads done

        if (kt + 64 < S_LEN) STAGE(cur ^ 1, kt + 64);

        const char* Kc = Ksh[cur];
        const char* Vc = Vsh[cur];

        // ---- S^T = K Q^T : 2 key-blocks x 4 k-steps of 32x32x16 ----
        f32x16 sacc[2];
        __builtin_amdgcn_s_setprio(1);
#pragma unroll
        for (int n0 = 0; n0 < 2; n0++) {
            f32x16 s = {};
            const char* Krow = Kc + (n0 * 32 + lo5) * 128;
#pragma unroll
            for (int ks = 0; ks < 4; ks++) {
                bf16x8 kf = *(const bf16x8*)(Krow + ((ks * 32 + hi * 16) ^ swr));
                s = __builtin_amdgcn_mfma_f32_32x32x16_bf16(kf, qf[ks], s, 0, 0, 0);
            }
            sacc[n0] = s;  // S[key=(r&3)+8*(r>>2)+4*hi + n0*32][q=lo5]
        }
        __builtin_amdgcn_s_setprio(0);

        // ---- fixed-max softmax + in-register P->PA (cvt_pk + permlane) ----
        bf16x8 pa[4];
#pragma unroll
        for (int n0 = 0; n0 < 2; n0++) {
            float p[16];
#pragma unroll
            for (int r = 0; r < 16; r++) {
                p[r] = __builtin_amdgcn_exp2f(sacc[n0][r] - EXPB);
            }
#pragma unroll
            for (int r = 0; r < 16; r += 4)
                lsum += (p[r] + p[r + 1]) + (p[r + 2] + p[r + 3]);
            unsigned c0, c1, c2, c3, c4, c5, c6, c7;
            asm("v_cvt_pk_bf16_f32 %0, %1, %2" : "=v"(c0) : "v"(p[0]),  "v"(p[1]));
            asm("v_cvt_pk_bf16_f32 %0, %1, %2" : "=v"(c1) : "v"(p[2]),  "v"(p[3]));
            asm("v_cvt_pk_bf16_f32 %0, %1, %2" : "=v"(c2) : "v"(p[4]),  "v"(p[5]));
            asm("v_cvt_pk_bf16_f32 %0, %1, %2" : "=v"(c3) : "v"(p[6]),  "v"(p[7]));
            asm("v_cvt_pk_bf16_f32 %0, %1, %2" : "=v"(c4) : "v"(p[8]),  "v"(p[9]));
            asm("v_cvt_pk_bf16_f32 %0, %1, %2" : "=v"(c5) : "v"(p[10]), "v"(p[11]));
            asm("v_cvt_pk_bf16_f32 %0, %1, %2" : "=v"(c6) : "v"(p[12]), "v"(p[13]));
            asm("v_cvt_pk_bf16_f32 %0, %1, %2" : "=v"(c7) : "v"(p[14]), "v"(p[15]));
            asm("v_permlane32_swap_b32 %0, %1" : "+v"(c0), "+v"(c2));
            asm("v_permlane32_swap_b32 %0, %1" : "+v"(c1), "+v"(c3));
            asm("v_permlane32_swap_b32 %0, %1" : "+v"(c4), "+v"(c6));
            asm("v_permlane32_swap_b32 %0, %1" : "+v"(c5), "+v"(c7));
            u32x4 w0 = {c0, c1, c2, c3};
            u32x4 w1 = {c4, c5, c6, c7};
            pa[n0 * 2]     = __builtin_bit_cast(bf16x8, w0);
            pa[n0 * 2 + 1] = __builtin_bit_cast(bf16x8, w1);
        }

        // ---- O += P V : 2 d-blocks x 4 k-steps ----
        __builtin_amdgcn_s_setprio(1);
#pragma unroll
        for (int db = 0; db < 2; db++) {
            const char* Vrow = Vc + (db * 32 + lo5) * 128;
#pragma unroll
            for (int ks = 0; ks < 4; ks++) {
                bf16x8 vf = *(const bf16x8*)(Vrow + ((ks * 32 + hi * 16) ^ swr));
                oacc[db] = __builtin_amdgcn_mfma_f32_32x32x16_bf16(
                    pa[ks], vf, oacc[db], 0, 0, 0);
            }
        }
        __builtin_amdgcn_s_setprio(0);
        cur ^= 1;
    }
#undef STAGE

    // lane l and l^32 hold complementary key-halves of q=lo5
    lsum += __shfl_xor(lsum, 32, 64);
    float inv = 1.f / lsum;  // valid for q = lo5

    // O store: oacc[db][r] is O[q=(r&3)+8*(r>>2)+4*hi][d=db*32+lo5]
#pragma unroll
    for (int r = 0; r < 16; r++) {
        int qr = (r & 3) + 8 * (r >> 2) + 4 * hi;
        float invr = __shfl(inv, qr, 32);
        int qrow = q0 + w * 32 + qr;
        long base = ((long)b * S_LEN + qrow) * EMB + h * HD;
        O[base + lo5]      = __float2bfloat16(oacc[0][r] * invr);
        O[base + 32 + lo5] = __float2bfloat16(oacc[1][r] * invr);
    }
}

extern "C" void kernel_launch(void* const* d_in, const int* in_sizes, int n_in,
                              void* d_out, int out_size, void* d_ws, size_t ws_size,
                              hipStream_t stream) {
    const float* x     = (const float*)d_in[0];   // [2,2048,1024]
    const float* qkv_w = (const float*)d_in[1];   // [3072,1024]
    const float* out_w = (const float*)d_in[2];   // [1024,1024]
    const float* qp    = (const float*)d_in[3];   // [64]
    float* out = (float*)d_out;                   // [2,2048,1024] fp32

    const long NELEM = (long)2 * S_LEN * EMB;     // 4,194,304
    __hip_bfloat16* Q   = (__hip_bfloat16*)d_ws;  // [B,H,S,D] (x 0.125*log2e)
    __hip_bfloat16* K   = Q + NELEM;              // [B,H,S,D]
    __hip_bfloat16* Vt  = K + NELEM;              // [B,H,D,S]
    __hip_bfloat16* O   = Vt + NELEM;             // [B,S,E]
    __hip_bfloat16* xb  = O + NELEM;              // [4096][1024]
    __hip_bfloat16* wqb = xb + NELEM;             // [3072][1024]
    __hip_bfloat16* wob = wqb + (long)3072 * 1024;// [1024][1024]

    dim3 blk(256);
    cvt_all<<<dim3(8192), blk, 0, stream>>>(x, qkv_w, out_w, xb, wqb, wob);
    gemm_mfma<0><<<dim3(3072 / 128, 4096 / 128), blk, 0, stream>>>(
        xb, wqb, qp, Q, K, Vt, nullptr);
    attn_mfma<<<dim3(S_LEN / 64, 32), dim3(128), 0, stream>>>(Q, K, Vt, O);
    gemm_mfma<1><<<dim3(1024 / 128, 4096 / 128), blk, 0, stream>>>(
        O, wob, nullptr, nullptr, nullptr, nullptr, out);
}